// Round 6
// baseline (746.639 us; speedup 1.0000x reference)
//
#include <hip/hip_runtime.h>
#include <math.h>

// Problem constants
#define N_TOKENS  16384
#define D_MODEL   4096
#define N_EXPERTS 64
#define CAPACITY  308          // ceil(1.2 * 16384 / 64)
#define BUCKET_CAP 1024

// GEMM config: MFMA 16x16x32 bf16, exact 3-way split / 6-product fp32 emulation.
// Block = 32 tokens x 64 experts, 2 waves (wave = 16 tokens x 64 experts).
// Split-K NK=8 (fallback 4) -> 4096 (2048) blocks, LDS 12 KB -> ~13 blocks/CU.
#define KTILE  64
#define MTILE  32

typedef __attribute__((ext_vector_type(8))) short bf16x8;
typedef __attribute__((ext_vector_type(4))) float f32x4;

__device__ __forceinline__ unsigned short bf16_rne(float f) {
    unsigned u = __float_as_uint(f);
    u += 0x7fffu + ((u >> 16) & 1u);
    return (unsigned short)(u >> 16);
}
__device__ __forceinline__ float bf16_to_f32(unsigned short h) {
    return __uint_as_float(((unsigned)h) << 16);
}
// Exact 3-way RNE split: f == hi + mid + lo (fp32 24-bit mantissa -> 8+8+8).
__device__ __forceinline__ void split3(float f, unsigned short& h,
                                       unsigned short& m, unsigned short& l) {
    h = bf16_rne(f);
    float r1 = f - bf16_to_f32(h);   // exact, <= 16 significant bits
    m = bf16_rne(r1);
    float r2 = r1 - bf16_to_f32(m);  // exact, <= 8 significant bits
    l = bf16_rne(r2);                // exact
}

// ---- split W once: W[64][4096] fp32 -> whi/wmid/wlo bf16 ----
__global__ __launch_bounds__(256) void wsplit_kernel(
    const float* __restrict__ W,
    unsigned short* __restrict__ whi, unsigned short* __restrict__ wmid,
    unsigned short* __restrict__ wlo)
{
    int i = (blockIdx.x * 256 + threadIdx.x) * 4;
    float4 w = *(const float4*)&W[i];
    float e[4] = {w.x, w.y, w.z, w.w};
    ushort4 h, m, l;
    unsigned short* hp = &h.x; unsigned short* mp = &m.x; unsigned short* lp = &l.x;
    #pragma unroll
    for (int j = 0; j < 4; j++) split3(e[j], hp[j], mp[j], lp[j]);
    *(ushort4*)&whi[i]  = h;
    *(ushort4*)&wmid[i] = m;
    *(ushort4*)&wlo[i]  = l;
}

// ---- main GEMM: x[16384][4096] @ W^T -> part[NK][16384][64] ----
__global__ __launch_bounds__(128, 8) void gemm_kernel(
    const float* __restrict__ x,
    const unsigned short* __restrict__ whi,
    const unsigned short* __restrict__ wmid,
    const unsigned short* __restrict__ wlo,
    float* __restrict__ part, int ksplit)
{
    // XOR-swizzled bf16 tiles: row = token (32), 8 chunks of 8 bf16 per row.
    // chunk (r,q) lives at ushort index r*64 + ((q ^ (r&7))*8) -> conflict-free b128.
    __shared__ unsigned short xhi[MTILE * KTILE];    // 4 KB
    __shared__ unsigned short xmid[MTILE * KTILE];   // 4 KB
    __shared__ unsigned short xlo[MTILE * KTILE];    // 4 KB

    const int tid   = threadIdx.x;
    const int tg    = blockIdx.x & 511;     // 512 token groups of 32
    const int nk    = blockIdx.x >> 9;      // k-split index
    const int tbase = tg * MTILE;
    const int kbase = nk * ksplit;
    const int lane  = tid & 63;
    const int wv    = tid >> 6;             // 0..1

    // staging: thread covers row sr (0..31), k = sk0..sk0+16
    const int sr  = tid >> 2;
    const int sk0 = (tid & 3) * 16;
    const int sq  = (tid & 3) * 2;
    const float* xsrc = &x[(size_t)(tbase + sr) * D_MODEL + kbase + sk0];

    // MFMA fragment indices (verified: A[m=lane&15][k=quad*8+j];
    // C/D row=quad*4+reg, col=lane&15)
    const int arow = wv * 16 + (lane & 15);   // token row within tile (0..31)
    const int akq  = lane >> 4;               // k-quad 0..3
    const int nrow = lane & 15;               // expert row within n-tile

    f32x4 acc[4];
    #pragma unroll
    for (int nt = 0; nt < 4; nt++)
        #pragma unroll
        for (int r = 0; r < 4; r++) acc[nt][r] = 0.f;

    float pf[16];
    {   // prefetch tile 0
        float4 a0 = *(const float4*)(xsrc);
        float4 a1 = *(const float4*)(xsrc + 4);
        float4 a2 = *(const float4*)(xsrc + 8);
        float4 a3 = *(const float4*)(xsrc + 12);
        pf[0]=a0.x; pf[1]=a0.y; pf[2]=a0.z; pf[3]=a0.w;
        pf[4]=a1.x; pf[5]=a1.y; pf[6]=a1.z; pf[7]=a1.w;
        pf[8]=a2.x; pf[9]=a2.y; pf[10]=a2.z; pf[11]=a2.w;
        pf[12]=a3.x; pf[13]=a3.y; pf[14]=a3.z; pf[15]=a3.w;
    }

    for (int kc = 0; kc < ksplit; kc += KTILE) {
        // ---- convert prefetched fp32 -> hi/mid/lo bf16, write swizzled LDS ----
        #pragma unroll
        for (int c = 0; c < 2; c++) {
            bf16x8 vh, vm, vl;
            #pragma unroll
            for (int j = 0; j < 8; j++) {
                unsigned short h, m, l;
                split3(pf[c * 8 + j], h, m, l);
                vh[j] = (short)h; vm[j] = (short)m; vl[j] = (short)l;
            }
            int p = (sq + c) ^ (sr & 7);
            *(bf16x8*)&xhi[sr * 64 + p * 8]  = vh;
            *(bf16x8*)&xmid[sr * 64 + p * 8] = vm;
            *(bf16x8*)&xlo[sr * 64 + p * 8]  = vl;
        }
        __syncthreads();

        // ---- issue prefetch of next tile (overlaps MFMA below) ----
        if (kc + KTILE < ksplit) {
            const float* nsrc = xsrc + kc + KTILE;
            float4 a0 = *(const float4*)(nsrc);
            float4 a1 = *(const float4*)(nsrc + 4);
            float4 a2 = *(const float4*)(nsrc + 8);
            float4 a3 = *(const float4*)(nsrc + 12);
            pf[0]=a0.x; pf[1]=a0.y; pf[2]=a0.z; pf[3]=a0.w;
            pf[4]=a1.x; pf[5]=a1.y; pf[6]=a1.z; pf[7]=a1.w;
            pf[8]=a2.x; pf[9]=a2.y; pf[10]=a2.z; pf[11]=a2.w;
            pf[12]=a3.x; pf[13]=a3.y; pf[14]=a3.z; pf[15]=a3.w;
        }

        // ---- MFMA: 2 k-steps of 32, 4 n-tiles, 6 products each ----
        #pragma unroll
        for (int s = 0; s < 2; s++) {
            int chA = (s * 4 + akq) ^ (arow & 7);
            bf16x8 ahi = *(bf16x8*)&xhi[arow * 64 + chA * 8];
            bf16x8 ami = *(bf16x8*)&xmid[arow * 64 + chA * 8];
            bf16x8 alo = *(bf16x8*)&xlo[arow * 64 + chA * 8];
            size_t koff = (size_t)(kbase + kc + s * 32 + akq * 8);
            #pragma unroll
            for (int nt = 0; nt < 4; nt++) {
                size_t boff = (size_t)(nt * 16 + nrow) * D_MODEL + koff;
                bf16x8 bhi = *(const bf16x8*)&whi[boff];
                bf16x8 bmi = *(const bf16x8*)&wmid[boff];
                bf16x8 blo = *(const bf16x8*)&wlo[boff];
                // magnitude-ordered: 1, 2^-8, 2^-8, 2^-16, 2^-16, 2^-16
                acc[nt] = __builtin_amdgcn_mfma_f32_16x16x32_bf16(ahi, bhi, acc[nt], 0, 0, 0);
                acc[nt] = __builtin_amdgcn_mfma_f32_16x16x32_bf16(ahi, bmi, acc[nt], 0, 0, 0);
                acc[nt] = __builtin_amdgcn_mfma_f32_16x16x32_bf16(ami, bhi, acc[nt], 0, 0, 0);
                acc[nt] = __builtin_amdgcn_mfma_f32_16x16x32_bf16(ahi, blo, acc[nt], 0, 0, 0);
                acc[nt] = __builtin_amdgcn_mfma_f32_16x16x32_bf16(ami, bmi, acc[nt], 0, 0, 0);
                acc[nt] = __builtin_amdgcn_mfma_f32_16x16x32_bf16(alo, bhi, acc[nt], 0, 0, 0);
            }
        }
        __syncthreads();
    }

    // ---- write partials: token = tbase + wv*16 + akq*4 + r, expert = nt*16 + nrow
    #pragma unroll
    for (int nt = 0; nt < 4; nt++) {
        #pragma unroll
        for (int r = 0; r < 4; r++) {
            int tok = tbase + wv * 16 + akq * 4 + r;
            part[((size_t)nk * N_TOKENS + tok) * N_EXPERTS + nt * 16 + nrow] = acc[nt][r];
        }
    }
}

// Combine partials + bias, softmax, top-2, bucket scatter, importance.
template <int NK>
__global__ __launch_bounds__(256) void topk_kernel(
    const float* __restrict__ part, const float* __restrict__ b,
    float* __restrict__ out_ids, float* __restrict__ out_gates,
    int* __restrict__ cnt, float* __restrict__ imp,
    float2* __restrict__ bucket, int bucket_cap,
    float* __restrict__ out_mask)
{
    __shared__ float imp_s[4][N_EXPERTS];
    __shared__ float res_g[4][16];
    __shared__ int   res_i[4][16];
    const int tid  = threadIdx.x;
    const int wave = tid >> 6;
    const int lane = tid & 63;
    const int tok0 = blockIdx.x * 32 + wave * 8;
    float impacc = 0.f;

    for (int j = 0; j < 8; j++) {
        int tok = tok0 + j;
        float v = b[lane];
        #pragma unroll
        for (int k = 0; k < NK; k++)
            v += part[((size_t)k * N_TOKENS + tok) * N_EXPERTS + lane];

        float m = v;
        #pragma unroll
        for (int s = 32; s > 0; s >>= 1) m = fmaxf(m, __shfl_xor(m, s));
        float p = expf(v - m);
        float sum = p;
        #pragma unroll
        for (int s = 32; s > 0; s >>= 1) sum += __shfl_xor(sum, s);
        float prob = p / sum;
        impacc += prob;

        float bp = prob; int bi = lane;
        #pragma unroll
        for (int s = 32; s > 0; s >>= 1) {
            float op = __shfl_xor(bp, s); int oi = __shfl_xor(bi, s);
            if (op > bp || (op == bp && oi < bi)) { bp = op; bi = oi; }
        }
        float p2 = (lane == bi) ? -1.f : prob;
        float bp2 = p2; int bi2 = lane;
        #pragma unroll
        for (int s = 32; s > 0; s >>= 1) {
            float op = __shfl_xor(bp2, s); int oi = __shfl_xor(bi2, s);
            if (op > bp2 || (op == bp2 && oi < bi2)) { bp2 = op; bi2 = oi; }
        }

        if (lane == 0) {
            res_g[wave][j * 2]     = bp;  res_i[wave][j * 2]     = bi;
            res_g[wave][j * 2 + 1] = bp2; res_i[wave][j * 2 + 1] = bi2;
        }
    }

    __builtin_amdgcn_wave_barrier();
    if (lane < 16) {
        int tok  = tok0 + (lane >> 1);
        int slot = tok * 2 + (lane & 1);
        float g  = res_g[wave][lane];
        int   id = res_i[wave][lane];
        out_ids[slot]   = (float)id;
        out_gates[slot] = g;
        int pos = atomicAdd(&cnt[id], 1);
        if (pos < bucket_cap)
            bucket[id * bucket_cap + pos] = make_float2(g, __int_as_float(slot));
        else
            out_mask[slot] = 0.f;
    }

    imp_s[wave][lane] = impacc;
    __syncthreads();
    if (wave == 0) {
        float s = imp_s[0][lane] + imp_s[1][lane] + imp_s[2][lane] + imp_s[3][lane];
        atomicAdd(&imp[lane], s);
    }
}

// One block per expert: exact lexsort rank via O(n^2) comparison in LDS.
__global__ __launch_bounds__(256) void capacity_kernel(
    const int* __restrict__ cnt, const float2* __restrict__ bucket,
    float* __restrict__ out_mask, int bucket_cap)
{
    __shared__ float g_s[BUCKET_CAP];
    __shared__ int   i_s[BUCKET_CAP];
    const int e = blockIdx.x;
    int n = cnt[e];
    if (n > bucket_cap) n = bucket_cap;

    for (int i = threadIdx.x; i < n; i += 256) {
        float2 r = bucket[e * bucket_cap + i];
        g_s[i] = r.x;
        i_s[i] = __float_as_int(r.y);
    }
    __syncthreads();

    for (int i = threadIdx.x; i < n; i += 256) {
        float gi = g_s[i]; int ii = i_s[i];
        int rank = 0;
        for (int j = 0; j < n; j++) {
            float gj = g_s[j]; int ij = i_s[j];
            rank += (gj > gi || (gj == gi && ij < ii)) ? 1 : 0;
        }
        out_mask[ii] = (rank < CAPACITY) ? 1.f : 0.f;
    }
}

__global__ void aux_kernel(const int* __restrict__ cnt,
                           const float* __restrict__ imp,
                           float* __restrict__ out_aux)
{
    int lane = threadIdx.x;
    float load = (float)min(cnt[lane], CAPACITY);
    float v = (float)N_EXPERTS * (imp[lane] / (float)N_TOKENS) * (load / (float)N_TOKENS);
    #pragma unroll
    for (int s = 32; s > 0; s >>= 1) v += __shfl_xor(v, s);
    if (lane == 0) out_aux[0] = v;
}

extern "C" void kernel_launch(void* const* d_in, const int* in_sizes, int n_in,
                              void* d_out, int out_size, void* d_ws, size_t ws_size,
                              hipStream_t stream) {
    const float* x = (const float*)d_in[0];
    const float* W = (const float*)d_in[1];
    const float* b = (const float*)d_in[2];

    float* out       = (float*)d_out;
    float* out_ids   = out;
    float* out_gates = out + 32768;
    float* out_aux   = out + 65536;
    float* out_mask  = out + 65537;

    // ws: [0,256) cnt | [256,512) imp | part NK*4MB | whi/wmid/wlo 3*512KB | buckets
    const size_t partN = (size_t)N_TOKENS * N_EXPERTS * sizeof(float);          // 4 MB
    const size_t wN    = (size_t)N_EXPERTS * D_MODEL * sizeof(unsigned short);  // 512 KB
    const size_t bktN  = (size_t)N_EXPERTS * BUCKET_CAP * sizeof(float2);       // 512 KB

    int NK = (ws_size >= 512 + 8 * partN + 3 * wN + bktN) ? 8 : 4;

    int*            cnt    = (int*)d_ws;
    float*          imp    = (float*)((char*)d_ws + 256);
    float*          part   = (float*)((char*)d_ws + 512);
    unsigned short* whi    = (unsigned short*)((char*)d_ws + 512 + NK * partN);
    unsigned short* wmid   = (unsigned short*)((char*)d_ws + 512 + NK * partN + wN);
    unsigned short* wlo    = (unsigned short*)((char*)d_ws + 512 + NK * partN + 2 * wN);
    float2*         bucket = (float2*)((char*)d_ws + 512 + NK * partN + 3 * wN);

    size_t used = 512 + NK * partN + 3 * wN;
    int bucket_cap = (ws_size > used) ? (int)((ws_size - used) / (N_EXPERTS * sizeof(float2))) : 0;
    if (bucket_cap > BUCKET_CAP) bucket_cap = BUCKET_CAP;

    hipMemsetAsync(d_ws, 0, 512, stream);

    wsplit_kernel<<<(N_EXPERTS * D_MODEL) / (256 * 4), 256, 0, stream>>>(W, whi, wmid, wlo);
    gemm_kernel<<<512 * NK, 128, 0, stream>>>(x, whi, wmid, wlo, part, D_MODEL / NK);
    if (NK == 8)
        topk_kernel<8><<<512, 256, 0, stream>>>(part, b, out_ids, out_gates,
                                                cnt, imp, bucket, bucket_cap, out_mask);
    else
        topk_kernel<4><<<512, 256, 0, stream>>>(part, b, out_ids, out_gates,
                                                cnt, imp, bucket, bucket_cap, out_mask);
    capacity_kernel<<<N_EXPERTS, 256, 0, stream>>>(cnt, bucket, out_mask, bucket_cap);
    aux_kernel<<<1, 64, 0, stream>>>(cnt, imp, out_aux);
}